// Round 2
// baseline (1080.794 us; speedup 1.0000x reference)
//
#include <hip/hip_runtime.h>
#include <hip/hip_bf16.h>

#define C_CH 32
#define K_TAPS 27
#define CONV_BLOCK 256
#define CONV_GRID 2048
#define GROUPS_PER_BLOCK (CONV_BLOCK / 32)

// Kernel 1: sparse conv (compacted tap loop) + per-channel sum/sumsq accumulation.
// 32 lanes per voxel: lane j computes output channel j. 2 voxels per wave64.
__global__ __launch_bounds__(CONV_BLOCK) void sparse_conv_kernel(
    const float* __restrict__ feat,   // [N, 32]
    const float* __restrict__ wt,     // [27, 32, 32]
    const int*   __restrict__ nbr,    // [N, 27]
    float* __restrict__ conv_out,     // [N, 32] (= d_out, pre-BN)
    float* __restrict__ stats,        // [0..31] sum, [32..63] sumsq
    int n)
{
    const int tid = threadIdx.x;
    const int j   = tid & 31;          // channel
    const int grp = tid >> 5;          // group (voxel slot) within block

    float psum = 0.0f, psq = 0.0f;

    for (int v = blockIdx.x * GROUPS_PER_BLOCK + grp; v < n;
         v += gridDim.x * GROUPS_PER_BLOCK) {

        // lane j (<27) loads tap j's neighbor row index
        int my_idx = (j < K_TAPS) ? nbr[(size_t)v * K_TAPS + j] : -1;

        // 27-bit active-tap mask for this group (wave = 2 groups)
        unsigned long long b = __ballot(my_idx >= 0);
        unsigned m = (unsigned)(b >> (tid & 32));

        float acc = 0.0f;
        while (m) {
            int k = __builtin_ctz(m);
            m &= m - 1;
            int idx = __shfl(my_idx, k, 32);   // uniform within group

            const float4* __restrict__ frow =
                (const float4*)(feat + (size_t)idx * C_CH);
            const float* __restrict__ wk = wt + k * (C_CH * C_CH) + j;

            #pragma unroll
            for (int s = 0; s < 8; ++s) {
                float4 f4 = frow[s];           // group-uniform broadcast load
                acc = fmaf(f4.x, wk[(4 * s + 0) * C_CH], acc);
                acc = fmaf(f4.y, wk[(4 * s + 1) * C_CH], acc);
                acc = fmaf(f4.z, wk[(4 * s + 2) * C_CH], acc);
                acc = fmaf(f4.w, wk[(4 * s + 3) * C_CH], acc);
            }
        }

        conv_out[(size_t)v * C_CH + j] = acc;
        psum += acc;
        psq  += acc * acc;
    }

    // lanes j and j+32 hold partials for the same channel -> combine
    psum += __shfl_xor(psum, 32);
    psq  += __shfl_xor(psq, 32);

    __shared__ float bsum[C_CH];
    __shared__ float bsq[C_CH];
    if (tid < C_CH) { bsum[tid] = 0.0f; bsq[tid] = 0.0f; }
    __syncthreads();
    if ((tid & 32) == 0) {                 // one contributor per wave-half
        atomicAdd(&bsum[j], psum);
        atomicAdd(&bsq[j],  psq);
    }
    __syncthreads();
    if (tid < C_CH) {
        atomicAdd(&stats[tid],        bsum[tid]);
        atomicAdd(&stats[C_CH + tid], bsq[tid]);
    }
}

// Kernel 2: finalize BN stats -> scale/shift (single tiny block)
__global__ void bn_finalize_kernel(const float* __restrict__ stats,
                                   float* __restrict__ ss,       // [0..31] scale, [32..63] shift
                                   const float* __restrict__ gamma,
                                   const float* __restrict__ beta,
                                   float inv_n)
{
    int j = threadIdx.x;
    if (j < C_CH) {
        float mean = stats[j] * inv_n;
        float var  = stats[C_CH + j] * inv_n - mean * mean;
        float sc   = gamma[j] * rsqrtf(var + 1e-4f);
        ss[j]        = sc;
        ss[C_CH + j] = beta[j] - mean * sc;
    }
}

// Kernel 3: in-place BN + ReLU over d_out, float4-vectorized
__global__ __launch_bounds__(256) void bn_apply_kernel(
    float* __restrict__ out, const float* __restrict__ ss, int total4)
{
    int e = blockIdx.x * blockDim.x + threadIdx.x;
    if (e < total4) {
        float4 v = ((float4*)out)[e];
        int c4 = e & 7;                            // which quad of the 32 channels
        float4 sc = ((const float4*)ss)[c4];
        float4 sh = ((const float4*)(ss + C_CH))[c4];
        v.x = fmaxf(fmaf(v.x, sc.x, sh.x), 0.0f);
        v.y = fmaxf(fmaf(v.y, sc.y, sh.y), 0.0f);
        v.z = fmaxf(fmaf(v.z, sc.z, sh.z), 0.0f);
        v.w = fmaxf(fmaf(v.w, sc.w, sh.w), 0.0f);
        ((float4*)out)[e] = v;
    }
}

extern "C" void kernel_launch(void* const* d_in, const int* in_sizes, int n_in,
                              void* d_out, int out_size, void* d_ws, size_t ws_size,
                              hipStream_t stream) {
    const float* feat  = (const float*)d_in[0];   // [N, 32]
    const float* wt    = (const float*)d_in[1];   // [27, 32, 32]
    const float* gamma = (const float*)d_in[2];   // [32]
    const float* beta  = (const float*)d_in[3];   // [32]
    const int*   nbr   = (const int*)d_in[4];     // [N, 27]

    float* out   = (float*)d_out;
    float* stats = (float*)d_ws;                  // 64 floats: sum, sumsq
    float* ss    = stats + 2 * C_CH;              // 64 floats: scale, shift

    const int n = in_sizes[0] / C_CH;

    // zero the stats accumulators (ws is poisoned before every call)
    hipMemsetAsync(d_ws, 0, 2 * C_CH * sizeof(float), stream);

    sparse_conv_kernel<<<CONV_GRID, CONV_BLOCK, 0, stream>>>(
        feat, wt, nbr, out, stats, n);

    bn_finalize_kernel<<<1, 64, 0, stream>>>(stats, ss, gamma, beta,
                                             1.0f / (float)n);

    const int total4 = n * C_CH / 4;
    bn_apply_kernel<<<(total4 + 255) / 256, 256, 0, stream>>>(out, ss, total4);
}

// Round 3
// 712.169 us; speedup vs baseline: 1.5176x; 1.5176x over previous
//
#include <hip/hip_runtime.h>
#include <hip/hip_bf16.h>

#define C_CH 32
#define K_TAPS 27
#define CONV_GRID 2048

typedef short bf16x8 __attribute__((ext_vector_type(8)));
typedef float f32x4 __attribute__((ext_vector_type(4)));

// ---------------------------------------------------------------------------
// Kernel 0: convert weights f32 -> bf16, laid out as ready-to-load MFMA
// B-fragments. Fragment element t: e=t&7, lane=(t>>3)&63, half=(t>>9)&1,
// k_tap=t>>10.  B[k=ci][n=j] mapping: ci=(lane>>4)*8+e, j=half*16+(lane&15).
// ---------------------------------------------------------------------------
__global__ __launch_bounds__(256) void convert_weights_kernel(
    const float* __restrict__ wt, short* __restrict__ wbf)
{
    int t = blockIdx.x * 256 + threadIdx.x;
    if (t < K_TAPS * 1024) {
        int e = t & 7, l = (t >> 3) & 63, half = (t >> 9) & 1, k = t >> 10;
        int ci = (l >> 4) * 8 + e;
        int j  = half * 16 + (l & 15);
        union { __hip_bfloat16 h; short s; } u;
        u.h = __float2bfloat16(wt[k * 1024 + ci * 32 + j]);
        wbf[t] = u.s;
    }
}

// ---------------------------------------------------------------------------
// Kernel 1: sparse conv via MFMA. One wave = 16 voxels.
// Per tap: A[16 voxels][32 ci] gathered bf16 rows, B = W[k] (2 N-halves),
// 2x mfma_f32_16x16x32_bf16 accumulate C[16][32].
// ---------------------------------------------------------------------------
__global__ __launch_bounds__(256) void conv_mfma_kernel(
    const float* __restrict__ feat,   // [N, 32] f32
    const short* __restrict__ wbf,    // bf16 B-fragments [27][2][64][8]
    const int*   __restrict__ nbr,    // [N, 27]
    float* __restrict__ out,          // [N, 32] (pre-BN)
    float* __restrict__ stats,        // [0..31] sum, [32..63] sumsq
    int n)
{
    __shared__ float bsum[C_CH];
    __shared__ float bsq[C_CH];
    const int tid = threadIdx.x;
    if (tid < C_CH) { bsum[tid] = 0.0f; bsq[tid] = 0.0f; }
    __syncthreads();

    const int l   = tid & 63;
    const int wv  = tid >> 6;
    const int row = l & 15;        // A-row / output voxel slot
    const int kq  = l >> 4;        // k-chunk 0..3
    const int n_batches   = (n + 15) >> 4;
    const int wave_gid    = blockIdx.x * 4 + wv;
    const int total_waves = gridDim.x * 4;

    float ps0 = 0.0f, ps1 = 0.0f, pq0 = 0.0f, pq1 = 0.0f;

    for (int b = wave_gid; b < n_batches; b += total_waves) {
        const int vbase = b << 4;
        const int myv   = vbase + row;
        const bool rowok = myv < n;

        // prefetch ALL 27 neighbor indices for my row (independent loads,
        // one latency exposure for the whole batch)
        int idxs[K_TAPS];
        #pragma unroll
        for (int k = 0; k < K_TAPS; ++k)
            idxs[k] = rowok ? nbr[(size_t)myv * K_TAPS + k] : -1;

        f32x4 acc0 = {0.f, 0.f, 0.f, 0.f};
        f32x4 acc1 = {0.f, 0.f, 0.f, 0.f};

        #pragma unroll
        for (int k = 0; k < K_TAPS; ++k) {
            const int idx = idxs[k];
            const bool valid = idx >= 0;
            if (__ballot(valid) == 0) continue;   // no voxel in batch has this tap

            bf16x8 a = {0, 0, 0, 0, 0, 0, 0, 0};
            if (valid) {
                const float4* fp =
                    (const float4*)(feat + (size_t)idx * C_CH + kq * 8);
                float4 f0 = fp[0];
                float4 f1 = fp[1];
                union { bf16x8 v; __hip_bfloat162 h[4]; } au;
                au.h[0] = __float22bfloat162_rn(make_float2(f0.x, f0.y));
                au.h[1] = __float22bfloat162_rn(make_float2(f0.z, f0.w));
                au.h[2] = __float22bfloat162_rn(make_float2(f1.x, f1.y));
                au.h[3] = __float22bfloat162_rn(make_float2(f1.z, f1.w));
                a = au.v;
            }

            bf16x8 b0 = *(const bf16x8*)(wbf + (((k * 2 + 0) * 64 + l) << 3));
            bf16x8 b1 = *(const bf16x8*)(wbf + (((k * 2 + 1) * 64 + l) << 3));

            acc0 = __builtin_amdgcn_mfma_f32_16x16x32_bf16(a, b0, acc0, 0, 0, 0);
            acc1 = __builtin_amdgcn_mfma_f32_16x16x32_bf16(a, b1, acc1, 0, 0, 0);
        }

        // C/D layout: col = lane&15, row = (lane>>4)*4 + r
        #pragma unroll
        for (int r = 0; r < 4; ++r) {
            const int orow = vbase + kq * 4 + r;
            if (orow < n) {
                const float v0 = acc0[r];
                const float v1 = acc1[r];
                out[(size_t)orow * C_CH + (l & 15)]      = v0;
                out[(size_t)orow * C_CH + 16 + (l & 15)] = v1;
                ps0 += v0; pq0 += v0 * v0;
                ps1 += v1; pq1 += v1 * v1;
            }
        }
    }

    // lanes {l, l^16, l^32, l^48} all hold the same channel pair -> combine
    ps0 += __shfl_xor(ps0, 16); ps0 += __shfl_xor(ps0, 32);
    ps1 += __shfl_xor(ps1, 16); ps1 += __shfl_xor(ps1, 32);
    pq0 += __shfl_xor(pq0, 16); pq0 += __shfl_xor(pq0, 32);
    pq1 += __shfl_xor(pq1, 16); pq1 += __shfl_xor(pq1, 32);

    if (l < 16) {
        atomicAdd(&bsum[l],      ps0);
        atomicAdd(&bsum[16 + l], ps1);
        atomicAdd(&bsq[l],       pq0);
        atomicAdd(&bsq[16 + l],  pq1);
    }
    __syncthreads();
    if (tid < C_CH) {
        atomicAdd(&stats[tid],        bsum[tid]);
        atomicAdd(&stats[C_CH + tid], bsq[tid]);
    }
}

// ---------------------------------------------------------------------------
// Kernel 2: finalize BN stats -> scale/shift
// ---------------------------------------------------------------------------
__global__ void bn_finalize_kernel(const float* __restrict__ stats,
                                   float* __restrict__ ss,
                                   const float* __restrict__ gamma,
                                   const float* __restrict__ beta,
                                   float inv_n)
{
    int j = threadIdx.x;
    if (j < C_CH) {
        float mean = stats[j] * inv_n;
        float var  = stats[C_CH + j] * inv_n - mean * mean;
        float sc   = gamma[j] * rsqrtf(var + 1e-4f);
        ss[j]        = sc;
        ss[C_CH + j] = beta[j] - mean * sc;
    }
}

// ---------------------------------------------------------------------------
// Kernel 3: in-place BN + ReLU, float4-vectorized
// ---------------------------------------------------------------------------
__global__ __launch_bounds__(256) void bn_apply_kernel(
    float* __restrict__ out, const float* __restrict__ ss, int total4)
{
    int e = blockIdx.x * blockDim.x + threadIdx.x;
    if (e < total4) {
        float4 v = ((float4*)out)[e];
        int c4 = e & 7;
        float4 sc = ((const float4*)ss)[c4];
        float4 sh = ((const float4*)(ss + C_CH))[c4];
        v.x = fmaxf(fmaf(v.x, sc.x, sh.x), 0.0f);
        v.y = fmaxf(fmaf(v.y, sc.y, sh.y), 0.0f);
        v.z = fmaxf(fmaf(v.z, sc.z, sh.z), 0.0f);
        v.w = fmaxf(fmaf(v.w, sc.w, sh.w), 0.0f);
        ((float4*)out)[e] = v;
    }
}

extern "C" void kernel_launch(void* const* d_in, const int* in_sizes, int n_in,
                              void* d_out, int out_size, void* d_ws, size_t ws_size,
                              hipStream_t stream) {
    const float* feat  = (const float*)d_in[0];   // [N, 32]
    const float* wt    = (const float*)d_in[1];   // [27, 32, 32]
    const float* gamma = (const float*)d_in[2];   // [32]
    const float* beta  = (const float*)d_in[3];   // [32]
    const int*   nbr   = (const int*)d_in[4];     // [N, 27]

    float* out   = (float*)d_out;
    float* stats = (float*)d_ws;                  // 64 f32: sum, sumsq
    float* ss    = stats + 2 * C_CH;              // 64 f32: scale, shift
    short* wbf   = (short*)(ss + 2 * C_CH);       // 27648 bf16 weight fragments

    const int n = in_sizes[0] / C_CH;

    hipMemsetAsync(stats, 0, 2 * C_CH * sizeof(float), stream);

    convert_weights_kernel<<<(K_TAPS * 1024 + 255) / 256, 256, 0, stream>>>(wt, wbf);

    conv_mfma_kernel<<<CONV_GRID, 256, 0, stream>>>(feat, wbf, nbr, out, stats, n);

    bn_finalize_kernel<<<1, 64, 0, stream>>>(stats, ss, gamma, beta,
                                             1.0f / (float)n);

    const int total4 = n * C_CH / 4;
    bn_apply_kernel<<<(total4 + 255) / 256, 256, 0, stream>>>(out, ss, total4);
}